// Round 2
// baseline (26.730 us; speedup 1.0000x reference)
//
#include <hip/hip_runtime.h>
#include <math.h>

#define NB 8      // batch
#define ND 256    // sequence length (i, j)
#define NN 64     // channels ("heads", head_dim = 1)
#define GROUPS 4
#define JT (ND / GROUPS)   // 64 j-values per thread

// One block per (b, n): 1024 threads = (row i = t&255) x (j-group g = t>>8).
// Each thread computes q,k,v for its row (redundant across groups), group 0
// publishes k,v to LDS; each thread then reduces exp(qs_i*k_j)*v_j over its
// 64-j slice; partials combine via LDS.
__global__ __launch_bounds__(1024, 8)
void fused_mhsa_kernel(const float* __restrict__ x,
                       const float* __restrict__ W,
                       float* __restrict__ out) {
    const int bn = blockIdx.x;        // 0..511
    const int b  = bn >> 6;
    const int n  = bn & 63;
    const int t  = threadIdx.x;       // 0..1023
    const int i  = t & 255;           // sequence row
    const int g  = t >> 8;            // j-group 0..3

    __shared__ float wq[NN], wk[NN], wv[NN];
    __shared__ __align__(16) float ks[ND];
    __shared__ __align__(16) float vs[ND];
    __shared__ float redmax[16], redmin[16];
    __shared__ float psum[GROUPS][ND];   // 4 KB
    __shared__ float pacc[GROUPS][ND];   // 4 KB

    // ---- stage the three W columns (n, 64+n, 128+n) into LDS ----
    if (t < 3 * NN) {
        const int which = t >> 6;     // 0:q 1:k 2:v
        const int m     = t & 63;
        const float val = W[m * (3 * NN) + which * NN + n];
        if (which == 0)      wq[m] = val;
        else if (which == 1) wk[m] = val;
        else                 wv[m] = val;
    }
    __syncthreads();

    // ---- q_i, k_i, v_i = dot(x[b,i,:], w{q,k,v}); redundant across groups ----
    const float4* xrow = reinterpret_cast<const float4*>(x + ((size_t)b * ND + i) * NN);
    float q = 0.f, k = 0.f, v = 0.f;
    #pragma unroll 4
    for (int m4 = 0; m4 < NN / 4; ++m4) {
        const float4 xv = xrow[m4];
        const int m = m4 * 4;
        q = fmaf(xv.x, wq[m+0], q); k = fmaf(xv.x, wk[m+0], k); v = fmaf(xv.x, wv[m+0], v);
        q = fmaf(xv.y, wq[m+1], q); k = fmaf(xv.y, wk[m+1], k); v = fmaf(xv.y, wv[m+1], v);
        q = fmaf(xv.z, wq[m+2], q); k = fmaf(xv.z, wk[m+2], k); v = fmaf(xv.z, wv[m+2], v);
        q = fmaf(xv.w, wq[m+3], q); k = fmaf(xv.w, wk[m+3], k); v = fmaf(xv.w, wv[m+3], v);
    }
    if (g == 0) { ks[i] = k; vs[i] = v; }

    // ---- block reduce kmax/kmin (row max of rank-1 scores = qs*kmax or qs*kmin) ----
    float kmax = k, kmin = k;
    #pragma unroll
    for (int off = 32; off > 0; off >>= 1) {
        kmax = fmaxf(kmax, __shfl_xor(kmax, off));
        kmin = fminf(kmin, __shfl_xor(kmin, off));
    }
    const int wave = t >> 6;          // 0..15
    if ((t & 63) == 0) { redmax[wave] = kmax; redmin[wave] = kmin; }
    __syncthreads();   // publishes ks/vs AND red*
    kmax = redmax[0]; kmin = redmin[0];
    #pragma unroll
    for (int w = 1; w < 16; ++w) {
        kmax = fmaxf(kmax, redmax[w]);
        kmin = fminf(kmin, redmin[w]);
    }

    // ---- partial softmax for row i over j in [g*64, g*64+64) ----
    const float LOG2E = 1.4426950408889634f;
    const float scale = 0.125f;                  // 1/sqrt(64)
    const float qs = q * scale * LOG2E;          // exponent in log2 domain
    const float nm2 = -fmaxf(qs * kmax, qs * kmin);

    float sum = 0.f, acc = 0.f;
    const float4* k4 = reinterpret_cast<const float4*>(ks) + g * (JT / 4);
    const float4* v4 = reinterpret_cast<const float4*>(vs) + g * (JT / 4);
    #pragma unroll 4
    for (int j4 = 0; j4 < JT / 4; ++j4) {
        const float4 kv = k4[j4];
        const float4 vv = v4[j4];
        const float e0 = __builtin_amdgcn_exp2f(fmaf(qs, kv.x, nm2));
        const float e1 = __builtin_amdgcn_exp2f(fmaf(qs, kv.y, nm2));
        const float e2 = __builtin_amdgcn_exp2f(fmaf(qs, kv.z, nm2));
        const float e3 = __builtin_amdgcn_exp2f(fmaf(qs, kv.w, nm2));
        sum += (e0 + e1) + (e2 + e3);
        acc = fmaf(e0, vv.x, acc);
        acc = fmaf(e1, vv.y, acc);
        acc = fmaf(e2, vv.z, acc);
        acc = fmaf(e3, vv.w, acc);
    }
    psum[g][i] = sum;
    pacc[g][i] = acc;
    __syncthreads();

    // ---- combine the 4 partials and write out (threads 0..255) ----
    if (t < ND) {
        float s = psum[0][t] + psum[1][t] + psum[2][t] + psum[3][t];
        float a = pacc[0][t] + pacc[1][t] + pacc[2][t] + pacc[3][t];
        out[((size_t)b * ND + t) * NN + n] = a / s;
    }
}

extern "C" void kernel_launch(void* const* d_in, const int* in_sizes, int n_in,
                              void* d_out, int out_size, void* d_ws, size_t ws_size,
                              hipStream_t stream) {
    const float* x = (const float*)d_in[0];   // (8, 256, 64) fp32
    const float* W = (const float*)d_in[1];   // (64, 192) fp32
    float* out = (float*)d_out;               // (8, 256, 64) fp32

    dim3 grid(NB * NN);   // 512 blocks, one per (b, n)
    dim3 block(GROUPS * ND);  // 1024 threads
    fused_mhsa_kernel<<<grid, block, 0, stream>>>(x, W, out);
}

// Round 3
// 15.504 us; speedup vs baseline: 1.7240x; 1.7240x over previous
//
#include <hip/hip_runtime.h>
#include <math.h>

#define NB 8      // batch
#define ND 256    // sequence length (i, j)
#define NN 64     // channels ("heads", head_dim = 1)

// One block per (b, n) pair: q,k,v columns via 64-wide dots with 3 columns of
// W, then a 256-way softmax-weighted average of v, fused. Softmax loop uses 4
// independent accumulator chains to break the serial FMA dependence.
__global__ __launch_bounds__(256, 2)
void fused_mhsa_kernel(const float* __restrict__ x,
                       const float* __restrict__ W,
                       float* __restrict__ out) {
    const int bn = blockIdx.x;        // 0..511
    const int b  = bn >> 6;
    const int n  = bn & 63;
    const int i  = threadIdx.x;       // sequence row 0..255

    __shared__ float wq[NN], wk[NN], wv[NN];
    __shared__ __align__(16) float ks[ND];
    __shared__ __align__(16) float vs[ND];
    __shared__ float red[8];          // per-wave kmax (0..3), kmin (4..7)

    // ---- stage the three W columns (n, 64+n, 128+n) into LDS ----
    if (i < 3 * NN) {
        const int which = i >> 6;     // 0:q 1:k 2:v
        const int m     = i & 63;
        const float val = W[m * (3 * NN) + which * NN + n];
        if (which == 0)      wq[m] = val;
        else if (which == 1) wk[m] = val;
        else                 wv[m] = val;
    }
    __syncthreads();

    // ---- per-thread q_i, k_i, v_i: dot(x[b,i,:], w{q,k,v}) single pass ----
    const float4* xrow = reinterpret_cast<const float4*>(x + ((size_t)b * ND + i) * NN);
    float q = 0.f, k = 0.f, v = 0.f;
    #pragma unroll
    for (int m4 = 0; m4 < NN / 4; ++m4) {
        const float4 xv = xrow[m4];
        const int m = m4 * 4;
        q = fmaf(xv.x, wq[m+0], q); k = fmaf(xv.x, wk[m+0], k); v = fmaf(xv.x, wv[m+0], v);
        q = fmaf(xv.y, wq[m+1], q); k = fmaf(xv.y, wk[m+1], k); v = fmaf(xv.y, wv[m+1], v);
        q = fmaf(xv.z, wq[m+2], q); k = fmaf(xv.z, wk[m+2], k); v = fmaf(xv.z, wv[m+2], v);
        q = fmaf(xv.w, wq[m+3], q); k = fmaf(xv.w, wk[m+3], k); v = fmaf(xv.w, wv[m+3], v);
    }
    ks[i] = k;
    vs[i] = v;

    // ---- block reduce kmax/kmin (rank-1 scores: row max = qs*kmax or qs*kmin) ----
    float kmax = k, kmin = k;
    #pragma unroll
    for (int off = 32; off > 0; off >>= 1) {
        kmax = fmaxf(kmax, __shfl_xor(kmax, off));
        kmin = fminf(kmin, __shfl_xor(kmin, off));
    }
    const int wave = i >> 6;
    if ((i & 63) == 0) { red[wave] = kmax; red[4 + wave] = kmin; }
    __syncthreads();   // publishes ks/vs AND red
    kmax = fmaxf(fmaxf(red[0], red[1]), fmaxf(red[2], red[3]));
    kmin = fminf(fminf(red[4], red[5]), fminf(red[6], red[7]));

    // ---- softmax row i over j, LDS broadcasts, 4 independent chains ----
    const float LOG2E = 1.4426950408889634f;
    const float scale = 0.125f;                  // 1/sqrt(64)
    const float qs = q * scale * LOG2E;          // exponent in log2 domain
    const float nm2 = -fmaxf(qs * kmax, qs * kmin);

    const float4* k4 = reinterpret_cast<const float4*>(ks);
    const float4* v4 = reinterpret_cast<const float4*>(vs);

    float s0 = 0.f, s1 = 0.f, s2 = 0.f, s3 = 0.f;
    float a0 = 0.f, a1 = 0.f, a2 = 0.f, a3 = 0.f;

    #pragma unroll
    for (int jj = 0; jj < ND / 16; ++jj) {       // 16 iterations, 16 j each
        const int base = jj * 4;
        const float4 ka = k4[base + 0];
        const float4 kb = k4[base + 1];
        const float4 kc = k4[base + 2];
        const float4 kd = k4[base + 3];
        const float4 va = v4[base + 0];
        const float4 vb = v4[base + 1];
        const float4 vc = v4[base + 2];
        const float4 vd = v4[base + 3];

        const float ea0 = __builtin_amdgcn_exp2f(fmaf(qs, ka.x, nm2));
        const float ea1 = __builtin_amdgcn_exp2f(fmaf(qs, ka.y, nm2));
        const float ea2 = __builtin_amdgcn_exp2f(fmaf(qs, ka.z, nm2));
        const float ea3 = __builtin_amdgcn_exp2f(fmaf(qs, ka.w, nm2));
        const float eb0 = __builtin_amdgcn_exp2f(fmaf(qs, kb.x, nm2));
        const float eb1 = __builtin_amdgcn_exp2f(fmaf(qs, kb.y, nm2));
        const float eb2 = __builtin_amdgcn_exp2f(fmaf(qs, kb.z, nm2));
        const float eb3 = __builtin_amdgcn_exp2f(fmaf(qs, kb.w, nm2));
        const float ec0 = __builtin_amdgcn_exp2f(fmaf(qs, kc.x, nm2));
        const float ec1 = __builtin_amdgcn_exp2f(fmaf(qs, kc.y, nm2));
        const float ec2 = __builtin_amdgcn_exp2f(fmaf(qs, kc.z, nm2));
        const float ec3 = __builtin_amdgcn_exp2f(fmaf(qs, kc.w, nm2));
        const float ed0 = __builtin_amdgcn_exp2f(fmaf(qs, kd.x, nm2));
        const float ed1 = __builtin_amdgcn_exp2f(fmaf(qs, kd.y, nm2));
        const float ed2 = __builtin_amdgcn_exp2f(fmaf(qs, kd.z, nm2));
        const float ed3 = __builtin_amdgcn_exp2f(fmaf(qs, kd.w, nm2));

        s0 += (ea0 + ea1) + (ea2 + ea3);
        s1 += (eb0 + eb1) + (eb2 + eb3);
        s2 += (ec0 + ec1) + (ec2 + ec3);
        s3 += (ed0 + ed1) + (ed2 + ed3);

        a0 = fmaf(ea0, va.x, a0); a0 = fmaf(ea1, va.y, a0);
        a0 = fmaf(ea2, va.z, a0); a0 = fmaf(ea3, va.w, a0);
        a1 = fmaf(eb0, vb.x, a1); a1 = fmaf(eb1, vb.y, a1);
        a1 = fmaf(eb2, vb.z, a1); a1 = fmaf(eb3, vb.w, a1);
        a2 = fmaf(ec0, vc.x, a2); a2 = fmaf(ec1, vc.y, a2);
        a2 = fmaf(ec2, vc.z, a2); a2 = fmaf(ec3, vc.w, a2);
        a3 = fmaf(ed0, vd.x, a3); a3 = fmaf(ed1, vd.y, a3);
        a3 = fmaf(ed2, vd.z, a3); a3 = fmaf(ed3, vd.w, a3);
    }

    const float sum = (s0 + s1) + (s2 + s3);
    const float acc = (a0 + a1) + (a2 + a3);
    out[((size_t)b * ND + i) * NN + n] = acc / sum;
}

extern "C" void kernel_launch(void* const* d_in, const int* in_sizes, int n_in,
                              void* d_out, int out_size, void* d_ws, size_t ws_size,
                              hipStream_t stream) {
    const float* x = (const float*)d_in[0];   // (8, 256, 64) fp32
    const float* W = (const float*)d_in[1];   // (64, 192) fp32
    float* out = (float*)d_out;               // (8, 256, 64) fp32

    dim3 grid(NB * NN);   // 512 blocks, one per (b, n)
    dim3 block(ND);       // 256 threads, one per sequence row
    fused_mhsa_kernel<<<grid, block, 0, stream>>>(x, W, out);
}